// Round 6
// baseline (579.027 us; speedup 1.0000x reference)
//
#include <hip/hip_runtime.h>
#include <cstdint>
#include <cstddef>

#define GRIDB 256
#define NTH   65536   // GRIDB*256

typedef __attribute__((ext_vector_type(8))) short bf16x8;
typedef __attribute__((ext_vector_type(4))) float f32x4;
typedef unsigned int uint_t;
typedef unsigned short ushort_t;

__device__ __forceinline__ ushort_t f2bf(float f) {
  uint_t u = __float_as_uint(f);
  u += 0x7fffu + ((u >> 16) & 1u);   // RNE
  return (ushort_t)(u >> 16);
}
__device__ __forceinline__ float bf2f(ushort_t h) {
  return __uint_as_float(((uint_t)h) << 16);
}
#define LOH(u) ((ushort_t)((u) & 0xffffu))
#define HIH(u) ((ushort_t)((u) >> 16))

// Workspace offsets (bytes)
#define OFF_W1   0           // 184320*16      = 2,949,120
#define OFF_WD   2949120     // 368640*16      = 5,898,240
#define OFF_XBF  8847360     // 2,359,296*2    = 4,718,592
#define OFF_XKB  13565952    //                = 4,718,592
#define OFF_PART 18284544    // 48*40960*4     = 7,864,320
#define OFF_VBF  26148864    // 160*256*2      = 81,920
#define OFF_AG   26230784    // 4*11520*4      = 184,320
#define OFF_BAR  26415104    // 2*4            = 8 (+pad)
#define WS_NEED  26415360

// zero the barrier state each call (replay-deterministic)
__global__ void k_init(uint_t* __restrict__ bar) { bar[0] = 0u; bar[1] = 0u; }

__global__ __launch_bounds__(256, 2) void k_fused(const float* __restrict__ x,
                                                  const float* __restrict__ W,
                                                  float* __restrict__ out,
                                                  char* __restrict__ wsb) {
  ushort_t* w1   = (ushort_t*)(wsb + OFF_W1);
  float*    wd   = (float*)(wsb + OFF_WD);
  ushort_t* xbf  = (ushort_t*)(wsb + OFF_XBF);
  ushort_t* xkb  = (ushort_t*)(wsb + OFF_XKB);
  float*    part = (float*)(wsb + OFF_PART);
  ushort_t* vbfT = (ushort_t*)(wsb + OFF_VBF);
  float*    ag   = (float*)(wsb + OFF_AG);
  uint_t*   bar  = (uint_t*)(wsb + OFF_BAR);

  const int bid = blockIdx.x, tid = threadIdx.x;
  const int gtid = bid * 256 + tid;
  __shared__ __align__(16) float sh[1056];   // transpose tile (32*33) / cw slice (192*2)
  __shared__ uint_t gen_s;
  if (tid == 0) gen_s = 0u;

  // grid barrier: capacity-resident (grid=256, >=2 blocks/CU by launch_bounds) +
  // agent-scope acq/rel flag. All calls are grid-uniform.
  auto gbar = [&]() {
    __syncthreads();
    if (tid == 0) {
      __threadfence();   // flush this block's writes (agent scope)
      uint_t gen = gen_s;
      uint_t arr = __hip_atomic_fetch_add(&bar[0], 1u, __ATOMIC_ACQ_REL, __HIP_MEMORY_SCOPE_AGENT);
      if (arr == GRIDB - 1) {
        __hip_atomic_store(&bar[0], 0u, __ATOMIC_RELAXED, __HIP_MEMORY_SCOPE_AGENT);
        __hip_atomic_store(&bar[1], gen + 1u, __ATOMIC_RELEASE, __HIP_MEMORY_SCOPE_AGENT);
      } else {
        while (__hip_atomic_load(&bar[1], __ATOMIC_ACQUIRE, __HIP_MEMORY_SCOPE_AGENT) < gen + 1u)
          __builtin_amdgcn_s_sleep(4);
      }
      __threadfence();
      gen_s = gen + 1u;
    }
    __syncthreads();
  };

  // ================= PREP =================
  // (a) w1: B-frag bf16 W.  w1[(kt*10+nt)*64+l][j] = W[c][nt][l&15][i], k=kt*32+8*(l>>4)+j
  for (int g = gtid; g < 184320; g += NTH) {
    int ll = g & 63, tile = g >> 6;
    int nt = tile % 10, kt = tile / 10;
    int lmm = ll & 15, lgg = ll >> 4;
    uint_t pk[4];
#pragma unroll
    for (int jj = 0; jj < 4; ++jj) {
      int k0 = kt * 32 + lgg * 8 + jj * 2;
      int i0 = k0 / 1152, c0 = k0 - i0 * 1152;
      int i1 = (k0 + 1) / 1152, c1 = (k0 + 1) - i1 * 1152;
      ushort_t e0 = f2bf(W[((size_t)(c0 * 10 + nt) * 16 + lmm) * 8 + i0]);
      ushort_t e1 = f2bf(W[((size_t)(c1 * 10 + nt) * 16 + lmm) * 8 + i1]);
      pk[jj] = (uint_t)e0 | ((uint_t)e1 << 16);
    }
    uint4 v; v.x = pk[0]; v.y = pk[1]; v.z = pk[2]; v.w = pk[3];
    *(uint4*)(w1 + (size_t)g * 8) = v;
  }
  // (b) wd: D-layout f32 W for gemm2 epilogue. krow = mt2*16 + 4*(l>>4) + r
  for (int g = gtid; g < 368640; g += NTH) {
    int ll = g & 63, tile = g >> 6;
    int nt = tile % 10, mt2 = tile / 10;
    int lmm = ll & 15, lgg = ll >> 4;
    float vv[4];
#pragma unroll
    for (int r = 0; r < 4; ++r) {
      int krow = mt2 * 16 + lgg * 4 + r;
      int i = krow / 1152, c = krow - i * 1152;
      vv[r] = W[((size_t)(c * 10 + nt) * 16 + lmm) * 8 + i];
    }
    *(float4*)(wd + (size_t)g * 4) = make_float4(vv[0], vv[1], vv[2], vv[3]);
  }
  // (c) xbf: row-major bf16 x
  for (int g = gtid; g < 294912; g += NTH) {
    const float4 a0 = *(const float4*)(x + (size_t)g * 8);
    const float4 a1 = *(const float4*)(x + (size_t)g * 8 + 4);
    uint4 pk;
    pk.x = (uint_t)f2bf(a0.x) | ((uint_t)f2bf(a0.y) << 16);
    pk.y = (uint_t)f2bf(a0.z) | ((uint_t)f2bf(a0.w) << 16);
    pk.z = (uint_t)f2bf(a1.x) | ((uint_t)f2bf(a1.y) << 16);
    pk.w = (uint_t)f2bf(a1.z) | ((uint_t)f2bf(a1.w) << 16);
    *(uint4*)(xbf + (size_t)g * 8) = pk;
  }
  // (d) zero all 4 per-iteration ag slices
  if (gtid < 46080) ag[gtid] = 0.f;
  // (e) xkb: transposed bf16 x, [9216][256]
  {
    int tx = tid & 31, ty = tid >> 5;
    for (int tb = bid; tb < 2304; tb += GRIDB) {   // 9 tiles per block, uniform
      int k0 = (tb % 288) * 32, b0 = (tb / 288) * 32;
      __syncthreads();
#pragma unroll
      for (int r = 0; r < 32; r += 8)
        sh[(ty + r) * 33 + tx] = x[(size_t)(b0 + ty + r) * 9216 + k0 + tx];
      __syncthreads();
#pragma unroll
      for (int r = 0; r < 32; r += 8)
        xkb[(size_t)(k0 + ty + r) * 256 + b0 + tx] = (ushort_t)f2bf(sh[tx * 33 + ty + r]);
    }
  }
  gbar();

  const int wv = tid >> 6, l = tid & 63;
  const int lm = l & 15, lgp = l >> 4;

  // ================= ROUTING ITERATIONS =================
  for (int it = 0; it < 4; ++it) {
    // ---------- G1: part[sp] = xbf * (cw .* W) ----------
    if (bid < 240) {
      int ntp = bid % 5, sp = bid / 5;
      // per-block softmax -> cw pair for this block's 192 c's (logits = sum(ag_t)/256)
      if (tid < 192) {
        int c = (sp % 6) * 192 + tid;
        float lv[10] = {0.f, 0.f, 0.f, 0.f, 0.f, 0.f, 0.f, 0.f, 0.f, 0.f};
        for (int t = 0; t < it; ++t) {
          const float* a = ag + t * 11520 + c * 10;
#pragma unroll
          for (int u = 0; u < 10; ++u) lv[u] += a[u];
        }
        float mx = lv[0];
#pragma unroll
        for (int u = 1; u < 10; ++u) mx = fmaxf(mx, lv[u]);
        float ssum = 0.f;
#pragma unroll
        for (int u = 0; u < 10; ++u) {
          lv[u] = __expf((lv[u] - mx) * (1.0f / 256.0f));  // = softmax(sum(ag)/256)
          ssum += lv[u];
        }
        float inv = 1.f / ssum;
        sh[tid * 2 + 0] = lv[ntp * 2 + 0] * inv;
        sh[tid * 2 + 1] = lv[ntp * 2 + 1] * inv;
      }
      __syncthreads();
      f32x4 z = {0.f, 0.f, 0.f, 0.f};
      f32x4 acc[4][2];
#pragma unroll
      for (int q = 0; q < 4; ++q) { acc[q][0] = z; acc[q][1] = z; }
      for (int ktl = 0; ktl < 6; ++ktl) {
        int kt = sp * 6 + ktl;
        bf16x8 af[4];
#pragma unroll
        for (int q = 0; q < 4; ++q)
          af[q] = *(const bf16x8*)(xbf + (size_t)(wv * 64 + q * 16 + lm) * 9216 + kt * 32 + lgp * 8);
        int cl = ktl * 32 + lgp * 8;
        const float4* cwv = (const float4*)&sh[cl * 2];
        float4 c01 = cwv[0], c23 = cwv[1], c45 = cwv[2], c67 = cwv[3];
        uint4 r0 = *(const uint4*)(w1 + ((size_t)(kt * 10 + ntp * 2 + 0)) * 512 + (size_t)l * 8);
        uint4 r1 = *(const uint4*)(w1 + ((size_t)(kt * 10 + ntp * 2 + 1)) * 512 + (size_t)l * 8);
        bf16x8 b0, b1;
        b0[0] = (short)f2bf(bf2f(LOH(r0.x)) * c01.x);
        b0[1] = (short)f2bf(bf2f(HIH(r0.x)) * c01.z);
        b0[2] = (short)f2bf(bf2f(LOH(r0.y)) * c23.x);
        b0[3] = (short)f2bf(bf2f(HIH(r0.y)) * c23.z);
        b0[4] = (short)f2bf(bf2f(LOH(r0.z)) * c45.x);
        b0[5] = (short)f2bf(bf2f(HIH(r0.z)) * c45.z);
        b0[6] = (short)f2bf(bf2f(LOH(r0.w)) * c67.x);
        b0[7] = (short)f2bf(bf2f(HIH(r0.w)) * c67.z);
        b1[0] = (short)f2bf(bf2f(LOH(r1.x)) * c01.y);
        b1[1] = (short)f2bf(bf2f(HIH(r1.x)) * c01.w);
        b1[2] = (short)f2bf(bf2f(LOH(r1.y)) * c23.y);
        b1[3] = (short)f2bf(bf2f(HIH(r1.y)) * c23.w);
        b1[4] = (short)f2bf(bf2f(LOH(r1.z)) * c45.y);
        b1[5] = (short)f2bf(bf2f(HIH(r1.z)) * c45.w);
        b1[6] = (short)f2bf(bf2f(LOH(r1.w)) * c67.y);
        b1[7] = (short)f2bf(bf2f(HIH(r1.w)) * c67.w);
#pragma unroll
        for (int q = 0; q < 4; ++q) {
          acc[q][0] = __builtin_amdgcn_mfma_f32_16x16x32_bf16(af[q], b0, acc[q][0], 0, 0, 0);
          acc[q][1] = __builtin_amdgcn_mfma_f32_16x16x32_bf16(af[q], b1, acc[q][1], 0, 0, 0);
        }
      }
      float* pb = part + (size_t)sp * 40960;
#pragma unroll
      for (int q = 0; q < 4; ++q)
#pragma unroll
        for (int nb = 0; nb < 2; ++nb)
#pragma unroll
          for (int r = 0; r < 4; ++r)
            pb[(size_t)(wv * 64 + q * 16 + lgp * 4 + r) * 160 + ntp * 32 + nb * 16 + lm] = acc[q][nb][r];
    }
    gbar();

    // ---------- R: reduce split-K + squash ----------
    if (bid < 160) {   // 160*256 = 40960 = BB*NN exactly
      float s = 0.f;
      for (int sp = 0; sp < 48; ++sp) s += part[(size_t)sp * 40960 + gtid];
      float n2 = s * s;
      n2 += __shfl_xor(n2, 1);
      n2 += __shfl_xor(n2, 2);
      n2 += __shfl_xor(n2, 4);
      n2 += __shfl_xor(n2, 8);
      float scale = n2 / ((1.f + n2) * sqrtf(n2));
      float vv = s * scale;
      if (it == 3) {
        out[gtid] = vv;
      } else {
        int b = gtid / 160, uo = gtid - b * 160;
        vbfT[(size_t)uo * 256 + b] = (ushort_t)f2bf(vv);
      }
    }
    if (it == 3) break;   // uniform across the grid; no barrier after final write
    gbar();

    // ---------- G2: agreement -> ag[it] ----------
    if (bid < 180) {
      int mb = bid / 5, ntp = bid % 5;
      f32x4 z = {0.f, 0.f, 0.f, 0.f};
      f32x4 acc[4][2];
#pragma unroll
      for (int q = 0; q < 4; ++q) { acc[q][0] = z; acc[q][1] = z; }
      for (int bt = 0; bt < 8; ++bt) {
        bf16x8 af[4];
#pragma unroll
        for (int q = 0; q < 4; ++q) {
          int mt2 = mb * 16 + wv * 4 + q;
          af[q] = *(const bf16x8*)(xkb + (size_t)(mt2 * 16 + lm) * 256 + bt * 32 + lgp * 8);
        }
        bf16x8 bfr[2];
#pragma unroll
        for (int nb = 0; nb < 2; ++nb)
          bfr[nb] = *(const bf16x8*)(vbfT + (size_t)(ntp * 32 + nb * 16 + lm) * 256 + bt * 32 + lgp * 8);
#pragma unroll
        for (int q = 0; q < 4; ++q) {
          acc[q][0] = __builtin_amdgcn_mfma_f32_16x16x32_bf16(af[q], bfr[0], acc[q][0], 0, 0, 0);
          acc[q][1] = __builtin_amdgcn_mfma_f32_16x16x32_bf16(af[q], bfr[1], acc[q][1], 0, 0, 0);
        }
      }
      float* agt = ag + it * 11520;
#pragma unroll
      for (int q = 0; q < 4; ++q) {
        int mt2 = mb * 16 + wv * 4 + q;
#pragma unroll
        for (int nb = 0; nb < 2; ++nb) {
          int nt = ntp * 2 + nb;
          float4 wdv = *(const float4*)(wd + ((size_t)(mt2 * 10 + nt) * 64 + l) * 4);
          float p0 = acc[q][nb][0] * wdv.x;
          float p1 = acc[q][nb][1] * wdv.y;
          float p2 = acc[q][nb][2] * wdv.z;
          float p3 = acc[q][nb][3] * wdv.w;
#pragma unroll
          for (int off = 1; off < 16; off <<= 1) {
            p0 += __shfl_xor(p0, off);
            p1 += __shfl_xor(p1, off);
            p2 += __shfl_xor(p2, off);
            p3 += __shfl_xor(p3, off);
          }
          if (lm == 0) {
            int krow = mt2 * 16 + lgp * 4;   // rows share i (16 | 1152)
            int c = krow % 1152;
            atomicAdd(&agt[(c + 0) * 10 + nt], p0);
            atomicAdd(&agt[(c + 1) * 10 + nt], p1);
            atomicAdd(&agt[(c + 2) * 10 + nt], p2);
            atomicAdd(&agt[(c + 3) * 10 + nt], p3);
          }
        }
      }
    }
    gbar();
  }
}

extern "C" void kernel_launch(void* const* d_in, const int* in_sizes, int n_in,
                              void* d_out, int out_size, void* d_ws, size_t ws_size,
                              hipStream_t stream) {
  const float* x = (const float*)d_in[0];
  const float* W = (const float*)d_in[1];
  float* out = (float*)d_out;
  char* ws = (char*)d_ws;
  if (ws_size < WS_NEED) return;   // output stays poisoned -> visible failure

  uint_t* bar = (uint_t*)(ws + OFF_BAR);
  k_init<<<dim3(1), dim3(64), 0, stream>>>(bar);
  k_fused<<<dim3(GRIDB), dim3(256), 0, stream>>>(x, W, out, ws);
}

// Round 7
// 358.630 us; speedup vs baseline: 1.6146x; 1.6146x over previous
//
#include <hip/hip_runtime.h>
#include <cstdint>
#include <cstddef>

#define GRIDB 256
#define NTH   65536   // GRIDB*256

typedef __attribute__((ext_vector_type(8))) short bf16x8;
typedef __attribute__((ext_vector_type(4))) float f32x4;
typedef unsigned int uint_t;
typedef unsigned short ushort_t;

__device__ __forceinline__ ushort_t f2bf(float f) {
  uint_t u = __float_as_uint(f);
  u += 0x7fffu + ((u >> 16) & 1u);   // RNE
  return (ushort_t)(u >> 16);
}
__device__ __forceinline__ float bf2f(ushort_t h) {
  return __uint_as_float(((uint_t)h) << 16);
}
#define LOH(u) ((ushort_t)((u) & 0xffffu))
#define HIH(u) ((ushort_t)((u) >> 16))

// Workspace offsets (bytes)
#define OFF_W1   0           // 184320*16      = 2,949,120
#define OFF_WD   2949120     // 368640*16      = 5,898,240
#define OFF_XBF  8847360     // 2,359,296*2    = 4,718,592
#define OFF_XKB  13565952    //                = 4,718,592
#define OFF_PART 18284544    // 48*40960*4     = 7,864,320
#define OFF_VBF  26148864    // 160*256*2      = 81,920
#define OFF_AG   26230784    // 4*11520*4      = 184,320
#define OFF_BAR  26415104    // 128B-aligned barrier line
#define WS_NEED  26415360

// ---------------- prep: W frags + ag/bar zero (high-occupancy) ----------------
__global__ void k_prep(const float* __restrict__ W, ushort_t* __restrict__ w1,
                       float* __restrict__ wd, float* __restrict__ ag,
                       uint_t* __restrict__ bar) {
  int gid = blockIdx.x * 256 + threadIdx.x;   // grid 2400*256 = 614400
  if (gid < 184320) {                         // w1: B-frag bf16 W
    int ll = gid & 63, tile = gid >> 6;
    int nt = tile % 10, kt = tile / 10;
    int lmm = ll & 15, lgg = ll >> 4;
    uint_t pk[4];
#pragma unroll
    for (int jj = 0; jj < 4; ++jj) {
      int k0 = kt * 32 + lgg * 8 + jj * 2;
      int i0 = k0 / 1152, c0 = k0 - i0 * 1152;
      int i1 = (k0 + 1) / 1152, c1 = (k0 + 1) - i1 * 1152;
      ushort_t e0 = f2bf(W[((size_t)(c0 * 10 + nt) * 16 + lmm) * 8 + i0]);
      ushort_t e1 = f2bf(W[((size_t)(c1 * 10 + nt) * 16 + lmm) * 8 + i1]);
      pk[jj] = (uint_t)e0 | ((uint_t)e1 << 16);
    }
    uint4 v; v.x = pk[0]; v.y = pk[1]; v.z = pk[2]; v.w = pk[3];
    *(uint4*)(w1 + (size_t)gid * 8) = v;
  } else if (gid < 552960) {                  // wd: D-layout f32 W
    int g2 = gid - 184320;
    int ll = g2 & 63, tile = g2 >> 6;
    int nt = tile % 10, mt2 = tile / 10;
    int lmm = ll & 15, lgg = ll >> 4;
    float vv[4];
#pragma unroll
    for (int r = 0; r < 4; ++r) {
      int krow = mt2 * 16 + lgg * 4 + r;
      int i = krow / 1152, c = krow - i * 1152;
      vv[r] = W[((size_t)(c * 10 + nt) * 16 + lmm) * 8 + i];
    }
    *(float4*)(wd + (size_t)g2 * 4) = make_float4(vv[0], vv[1], vv[2], vv[3]);
  } else if (gid < 599040) {                  // zero 4 ag slices (46080)
    ag[gid - 552960] = 0.f;
  } else if (gid == 599040) {                 // zero barrier counter
    bar[0] = 0u;
  }
}

// ---------------- x (fp32 row-major) -> xbf (bf16 row-major) ----------------
__global__ void k_xbf(const float* __restrict__ x, ushort_t* __restrict__ xbf) {
  int t = blockIdx.x * 256 + threadIdx.x;     // 294912 threads, 8 elems each
  const float4 a0 = *(const float4*)(x + (size_t)t * 8);
  const float4 a1 = *(const float4*)(x + (size_t)t * 8 + 4);
  uint4 pk;
  pk.x = (uint_t)f2bf(a0.x) | ((uint_t)f2bf(a0.y) << 16);
  pk.y = (uint_t)f2bf(a0.z) | ((uint_t)f2bf(a0.w) << 16);
  pk.z = (uint_t)f2bf(a1.x) | ((uint_t)f2bf(a1.y) << 16);
  pk.w = (uint_t)f2bf(a1.z) | ((uint_t)f2bf(a1.w) << 16);
  *(uint4*)(xbf + (size_t)t * 8) = pk;
}

// ---------------- transpose x[256][9216] -> xkb[9216][256] (bf16) ----------------
__global__ void k_xkb(const float* __restrict__ x, ushort_t* __restrict__ xkb) {
  __shared__ float tile[32][33];
  int k0 = blockIdx.x * 32, b0 = blockIdx.y * 32;
  int tx = threadIdx.x, ty = threadIdx.y;
#pragma unroll
  for (int r = 0; r < 32; r += 8)
    tile[ty + r][tx] = x[(size_t)(b0 + ty + r) * 9216 + k0 + tx];
  __syncthreads();
#pragma unroll
  for (int r = 0; r < 32; r += 8)
    xkb[(size_t)(k0 + ty + r) * 256 + b0 + tx] = (ushort_t)f2bf(tile[tx][ty + r]);
}

// ---------------- persistent routing kernel (10 grid barriers) ----------------
__global__ __launch_bounds__(256) void k_route(float* __restrict__ out,
                                               char* __restrict__ wsb) {
  ushort_t* w1   = (ushort_t*)(wsb + OFF_W1);
  float*    wd   = (float*)(wsb + OFF_WD);
  ushort_t* xbf  = (ushort_t*)(wsb + OFF_XBF);
  ushort_t* xkb  = (ushort_t*)(wsb + OFF_XKB);
  float*    part = (float*)(wsb + OFF_PART);
  ushort_t* vbfT = (ushort_t*)(wsb + OFF_VBF);
  float*    ag   = (float*)(wsb + OFF_AG);
  uint_t*   bar  = (uint_t*)(wsb + OFF_BAR);

  const int bid = blockIdx.x, tid = threadIdx.x;
  const int gtid = bid * 256 + tid;
  __shared__ __align__(16) float sh[512];   // cw slice (192*2)

  uint_t nbar = 0;
  // Monotonic grid barrier: RELAXED spin (no per-poll cache maintenance),
  // one agent fence each side. Grid=256=1 block/CU -> all resident by capacity.
  auto gbar = [&]() {
    __syncthreads();
    ++nbar;
    if (tid == 0) {
      __threadfence();   // publish this block's writes (L2 wb, agent scope)
      uint_t target = nbar * (uint_t)GRIDB;
      uint_t arr = __hip_atomic_fetch_add(&bar[0], 1u, __ATOMIC_RELAXED, __HIP_MEMORY_SCOPE_AGENT);
      if (arr != target - 1u) {
        while (__hip_atomic_load(&bar[0], __ATOMIC_RELAXED, __HIP_MEMORY_SCOPE_AGENT) < target)
          __builtin_amdgcn_s_sleep(8);
      }
      __threadfence();   // invalidate stale caches before consuming remote data
    }
    __syncthreads();
  };

  const int wv = tid >> 6, l = tid & 63;
  const int lm = l & 15, lgp = l >> 4;

  for (int it = 0; it < 4; ++it) {
    // ---------- G1: part[sp] = xbf * (cw .* W) ----------
    if (bid < 240) {
      int ntp = bid % 5, sp = bid / 5;
      // per-block softmax -> cw pair for this block's 192 c's (logits = sum(ag_t)/256)
      if (tid < 192) {
        int c = (sp % 6) * 192 + tid;
        float lv[10] = {0.f, 0.f, 0.f, 0.f, 0.f, 0.f, 0.f, 0.f, 0.f, 0.f};
        for (int t = 0; t < it; ++t) {
          const float* a = ag + t * 11520 + c * 10;
#pragma unroll
          for (int u = 0; u < 10; ++u) lv[u] += a[u];
        }
        float mx = lv[0];
#pragma unroll
        for (int u = 1; u < 10; ++u) mx = fmaxf(mx, lv[u]);
        float ssum = 0.f;
#pragma unroll
        for (int u = 0; u < 10; ++u) {
          lv[u] = __expf((lv[u] - mx) * (1.0f / 256.0f));  // softmax(sum(ag)/256)
          ssum += lv[u];
        }
        float inv = 1.f / ssum;
        sh[tid * 2 + 0] = lv[ntp * 2 + 0] * inv;
        sh[tid * 2 + 1] = lv[ntp * 2 + 1] * inv;
      }
      __syncthreads();
      f32x4 z = {0.f, 0.f, 0.f, 0.f};
      f32x4 acc[4][2];
#pragma unroll
      for (int q = 0; q < 4; ++q) { acc[q][0] = z; acc[q][1] = z; }
      for (int ktl = 0; ktl < 6; ++ktl) {
        int kt = sp * 6 + ktl;
        bf16x8 af[4];
#pragma unroll
        for (int q = 0; q < 4; ++q)
          af[q] = *(const bf16x8*)(xbf + (size_t)(wv * 64 + q * 16 + lm) * 9216 + kt * 32 + lgp * 8);
        int cl = ktl * 32 + lgp * 8;
        const float4* cwv = (const float4*)&sh[cl * 2];
        float4 c01 = cwv[0], c23 = cwv[1], c45 = cwv[2], c67 = cwv[3];
        uint4 r0 = *(const uint4*)(w1 + ((size_t)(kt * 10 + ntp * 2 + 0)) * 512 + (size_t)l * 8);
        uint4 r1 = *(const uint4*)(w1 + ((size_t)(kt * 10 + ntp * 2 + 1)) * 512 + (size_t)l * 8);
        bf16x8 b0, b1;
        b0[0] = (short)f2bf(bf2f(LOH(r0.x)) * c01.x);
        b0[1] = (short)f2bf(bf2f(HIH(r0.x)) * c01.z);
        b0[2] = (short)f2bf(bf2f(LOH(r0.y)) * c23.x);
        b0[3] = (short)f2bf(bf2f(HIH(r0.y)) * c23.z);
        b0[4] = (short)f2bf(bf2f(LOH(r0.z)) * c45.x);
        b0[5] = (short)f2bf(bf2f(HIH(r0.z)) * c45.z);
        b0[6] = (short)f2bf(bf2f(LOH(r0.w)) * c67.x);
        b0[7] = (short)f2bf(bf2f(HIH(r0.w)) * c67.z);
        b1[0] = (short)f2bf(bf2f(LOH(r1.x)) * c01.y);
        b1[1] = (short)f2bf(bf2f(HIH(r1.x)) * c01.w);
        b1[2] = (short)f2bf(bf2f(LOH(r1.y)) * c23.y);
        b1[3] = (short)f2bf(bf2f(HIH(r1.y)) * c23.w);
        b1[4] = (short)f2bf(bf2f(LOH(r1.z)) * c45.y);
        b1[5] = (short)f2bf(bf2f(HIH(r1.z)) * c45.w);
        b1[6] = (short)f2bf(bf2f(LOH(r1.w)) * c67.y);
        b1[7] = (short)f2bf(bf2f(HIH(r1.w)) * c67.w);
#pragma unroll
        for (int q = 0; q < 4; ++q) {
          acc[q][0] = __builtin_amdgcn_mfma_f32_16x16x32_bf16(af[q], b0, acc[q][0], 0, 0, 0);
          acc[q][1] = __builtin_amdgcn_mfma_f32_16x16x32_bf16(af[q], b1, acc[q][1], 0, 0, 0);
        }
      }
      float* pb = part + (size_t)sp * 40960;
#pragma unroll
      for (int q = 0; q < 4; ++q)
#pragma unroll
        for (int nb = 0; nb < 2; ++nb)
#pragma unroll
          for (int r = 0; r < 4; ++r)
            pb[(size_t)(wv * 64 + q * 16 + lgp * 4 + r) * 160 + ntp * 32 + nb * 16 + lm] = acc[q][nb][r];
    }
    gbar();

    // ---------- R: reduce split-K + squash ----------
    if (bid < 160) {   // 160*256 = 40960 = BB*NN exactly
      float s = 0.f;
      for (int sp = 0; sp < 48; ++sp) s += part[(size_t)sp * 40960 + gtid];
      float n2 = s * s;
      n2 += __shfl_xor(n2, 1);
      n2 += __shfl_xor(n2, 2);
      n2 += __shfl_xor(n2, 4);
      n2 += __shfl_xor(n2, 8);
      float scale = n2 / ((1.f + n2) * sqrtf(n2));
      float vv = s * scale;
      if (it == 3) {
        out[gtid] = vv;
      } else {
        int b = gtid / 160, uo = gtid - b * 160;
        vbfT[(size_t)uo * 256 + b] = (ushort_t)f2bf(vv);
      }
    }
    if (it == 3) break;   // uniform across the grid
    gbar();

    // ---------- G2: agreement -> ag[it] ----------
    if (bid < 180) {
      int mb = bid / 5, ntp = bid % 5;
      f32x4 z = {0.f, 0.f, 0.f, 0.f};
      f32x4 acc[4][2];
#pragma unroll
      for (int q = 0; q < 4; ++q) { acc[q][0] = z; acc[q][1] = z; }
      for (int bt = 0; bt < 8; ++bt) {
        bf16x8 af[4];
#pragma unroll
        for (int q = 0; q < 4; ++q) {
          int mt2 = mb * 16 + wv * 4 + q;
          af[q] = *(const bf16x8*)(xkb + (size_t)(mt2 * 16 + lm) * 256 + bt * 32 + lgp * 8);
        }
        bf16x8 bfr[2];
#pragma unroll
        for (int nb = 0; nb < 2; ++nb)
          bfr[nb] = *(const bf16x8*)(vbfT + (size_t)(ntp * 32 + nb * 16 + lm) * 256 + bt * 32 + lgp * 8);
#pragma unroll
        for (int q = 0; q < 4; ++q) {
          acc[q][0] = __builtin_amdgcn_mfma_f32_16x16x32_bf16(af[q], bfr[0], acc[q][0], 0, 0, 0);
          acc[q][1] = __builtin_amdgcn_mfma_f32_16x16x32_bf16(af[q], bfr[1], acc[q][1], 0, 0, 0);
        }
      }
      float* agt = ag + it * 11520;
#pragma unroll
      for (int q = 0; q < 4; ++q) {
        int mt2 = mb * 16 + wv * 4 + q;
#pragma unroll
        for (int nb = 0; nb < 2; ++nb) {
          int nt = ntp * 2 + nb;
          float4 wdv = *(const float4*)(wd + ((size_t)(mt2 * 10 + nt) * 64 + l) * 4);
          float p0 = acc[q][nb][0] * wdv.x;
          float p1 = acc[q][nb][1] * wdv.y;
          float p2 = acc[q][nb][2] * wdv.z;
          float p3 = acc[q][nb][3] * wdv.w;
#pragma unroll
          for (int off = 1; off < 16; off <<= 1) {
            p0 += __shfl_xor(p0, off);
            p1 += __shfl_xor(p1, off);
            p2 += __shfl_xor(p2, off);
            p3 += __shfl_xor(p3, off);
          }
          if (lm == 0) {
            int krow = mt2 * 16 + lgp * 4;   // rows share i (16 | 1152)
            int c = krow % 1152;
            atomicAdd(&agt[(c + 0) * 10 + nt], p0);
            atomicAdd(&agt[(c + 1) * 10 + nt], p1);
            atomicAdd(&agt[(c + 2) * 10 + nt], p2);
            atomicAdd(&agt[(c + 3) * 10 + nt], p3);
          }
        }
      }
    }
    gbar();
  }
}

extern "C" void kernel_launch(void* const* d_in, const int* in_sizes, int n_in,
                              void* d_out, int out_size, void* d_ws, size_t ws_size,
                              hipStream_t stream) {
  const float* x = (const float*)d_in[0];
  const float* W = (const float*)d_in[1];
  float* out = (float*)d_out;
  char* ws = (char*)d_ws;
  if (ws_size < WS_NEED) return;   // output stays poisoned -> visible failure

  ushort_t* w1  = (ushort_t*)(ws + OFF_W1);
  float*    wd  = (float*)(ws + OFF_WD);
  ushort_t* xbf = (ushort_t*)(ws + OFF_XBF);
  ushort_t* xkb = (ushort_t*)(ws + OFF_XKB);
  float*    ag  = (float*)(ws + OFF_AG);
  uint_t*   bar = (uint_t*)(ws + OFF_BAR);

  k_prep<<<dim3(2400), dim3(256), 0, stream>>>(W, w1, wd, ag, bar);
  k_xbf <<<dim3(1152), dim3(256), 0, stream>>>(x, xbf);
  k_xkb <<<dim3(288, 8), dim3(32, 8), 0, stream>>>(x, xkb);
  k_route<<<dim3(GRIDB), dim3(256), 0, stream>>>(out, ws);
}

// Round 8
// 248.513 us; speedup vs baseline: 2.3300x; 1.4431x over previous
//
#include <hip/hip_runtime.h>
#include <cstdint>
#include <cstddef>

typedef __attribute__((ext_vector_type(8))) short bf16x8;
typedef __attribute__((ext_vector_type(4))) float f32x4;
typedef unsigned int uint_t;
typedef unsigned short ushort_t;

__device__ __forceinline__ ushort_t f2bf(float f) {
  uint_t u = __float_as_uint(f);
  u += 0x7fffu + ((u >> 16) & 1u);   // RNE
  return (ushort_t)(u >> 16);
}
__device__ __forceinline__ float bf2f(ushort_t h) {
  return __uint_as_float(((uint_t)h) << 16);
}
#define LOH(u) ((ushort_t)((u) & 0xffffu))
#define HIH(u) ((ushort_t)((u) >> 16))

// Workspace offsets (bytes)
#define OFF_W1   0           // 184320*16   = 2,949,120
#define OFF_WD   2949120     // 368640*16   = 5,898,240
#define OFF_XBF  8847360     // 4,718,592
#define OFF_XKB  13565952    // 4,718,592
#define OFF_PART 18284544    // 48*40960*4  = 7,864,320
#define OFF_VBF  26148864    // 160*256*2   = 81,920
#define OFF_AG   26230784    // 4*11520*4   = 184,320
#define WS_NEED  26415104

// ---------------- setup: W frags + xbf + xkb + ag zero (one launch) ----------------
__global__ void k_setup(const float* __restrict__ x, const float* __restrict__ W,
                        ushort_t* __restrict__ w1, float* __restrict__ wd,
                        ushort_t* __restrict__ xbf, ushort_t* __restrict__ xkb,
                        float* __restrict__ ag) {
  int bid = blockIdx.x, tid = threadIdx.x;
  if (bid < 720) {                       // w1: B-frag bf16 W (184320 frag-lanes)
    int gid = bid * 256 + tid;
    int ll = gid & 63, tile = gid >> 6;
    int nt = tile % 10, kt = tile / 10;
    int lmm = ll & 15, lgg = ll >> 4;
    uint_t pk[4];
#pragma unroll
    for (int jj = 0; jj < 4; ++jj) {
      int k0 = kt * 32 + lgg * 8 + jj * 2;
      int i0 = k0 / 1152, c0 = k0 - i0 * 1152;
      int i1 = (k0 + 1) / 1152, c1 = (k0 + 1) - i1 * 1152;
      ushort_t e0 = f2bf(W[((size_t)(c0 * 10 + nt) * 16 + lmm) * 8 + i0]);
      ushort_t e1 = f2bf(W[((size_t)(c1 * 10 + nt) * 16 + lmm) * 8 + i1]);
      pk[jj] = (uint_t)e0 | ((uint_t)e1 << 16);
    }
    uint4 v; v.x = pk[0]; v.y = pk[1]; v.z = pk[2]; v.w = pk[3];
    *(uint4*)(w1 + (size_t)gid * 8) = v;
  } else if (bid < 2160) {               // wd: D-layout f32 W (368640 frag-lanes)
    int g2 = (bid - 720) * 256 + tid;
    int ll = g2 & 63, tile = g2 >> 6;
    int nt = tile % 10, mt2 = tile / 10;
    int lmm = ll & 15, lgg = ll >> 4;
    float vv[4];
#pragma unroll
    for (int r = 0; r < 4; ++r) {
      int krow = mt2 * 16 + lgg * 4 + r;
      int i = krow / 1152, c = krow - i * 1152;
      vv[r] = W[((size_t)(c * 10 + nt) * 16 + lmm) * 8 + i];
    }
    *(float4*)(wd + (size_t)g2 * 4) = make_float4(vv[0], vv[1], vv[2], vv[3]);
  } else if (bid < 2340) {               // zero 4 ag slices (46080)
    ag[(bid - 2160) * 256 + tid] = 0.f;
  } else if (bid < 3492) {               // xbf: row-major bf16 x (294912 x8-items)
    int t = (bid - 2340) * 256 + tid;
    const float4 a0 = *(const float4*)(x + (size_t)t * 8);
    const float4 a1 = *(const float4*)(x + (size_t)t * 8 + 4);
    uint4 pk;
    pk.x = (uint_t)f2bf(a0.x) | ((uint_t)f2bf(a0.y) << 16);
    pk.y = (uint_t)f2bf(a0.z) | ((uint_t)f2bf(a0.w) << 16);
    pk.z = (uint_t)f2bf(a1.x) | ((uint_t)f2bf(a1.y) << 16);
    pk.w = (uint_t)f2bf(a1.z) | ((uint_t)f2bf(a1.w) << 16);
    *(uint4*)(xbf + (size_t)t * 8) = pk;
  } else {                               // xkb: transpose tiles (2304 tiles)
    __shared__ float sh[32 * 33];
    int tb = bid - 3492;
    int k0 = (tb % 288) * 32, b0 = (tb / 288) * 32;
    int tx = tid & 31, ty = tid >> 5;
#pragma unroll
    for (int r = 0; r < 32; r += 8)
      sh[(ty + r) * 33 + tx] = x[(size_t)(b0 + ty + r) * 9216 + k0 + tx];
    __syncthreads();
#pragma unroll
    for (int r = 0; r < 32; r += 8)
      xkb[(size_t)(k0 + ty + r) * 256 + b0 + tx] = (ushort_t)f2bf(sh[tx * 33 + ty + r]);
  }
}

// ---------------- G1: part[sp] = xbf * (softmax(ag).*W), full-N per block ----------------
// grid (4 mb4, 48 sp), 256 thr = 4 waves; wave = 16 rows x 160 cols; K-chunk 192.
__global__ __launch_bounds__(256) void k_g1(const ushort_t* __restrict__ xbf,
                                            const ushort_t* __restrict__ w1,
                                            const float* __restrict__ ag,
                                            float* __restrict__ part, int it) {
  int mb4 = blockIdx.x, sp = blockIdx.y;
  int tid = threadIdx.x;
  int wv = tid >> 6, l = tid & 63, lm = l & 15, lgp = l >> 4;
  __shared__ float cwl[192 * 10];
  if (tid < 192) {   // softmax(sum_t ag_t / 256) for this block's 192 c's
    int c = (sp % 6) * 192 + tid;
    float lv[10] = {0.f, 0.f, 0.f, 0.f, 0.f, 0.f, 0.f, 0.f, 0.f, 0.f};
    for (int t = 0; t < it; ++t) {
      const float* a = ag + t * 11520 + c * 10;
#pragma unroll
      for (int u = 0; u < 10; ++u) lv[u] += a[u];
    }
    float mx = lv[0];
#pragma unroll
    for (int u = 1; u < 10; ++u) mx = fmaxf(mx, lv[u]);
    float ssum = 0.f;
#pragma unroll
    for (int u = 0; u < 10; ++u) {
      lv[u] = __expf((lv[u] - mx) * (1.0f / 256.0f));
      ssum += lv[u];
    }
    float inv = 1.f / ssum;
#pragma unroll
    for (int u = 0; u < 10; ++u) cwl[tid * 10 + u] = lv[u] * inv;
  }
  __syncthreads();
  f32x4 z = {0.f, 0.f, 0.f, 0.f};
  f32x4 acc[10];
#pragma unroll
  for (int nt = 0; nt < 10; ++nt) acc[nt] = z;
  int m0 = mb4 * 64 + wv * 16;
  for (int ktl = 0; ktl < 6; ++ktl) {
    int kt = sp * 6 + ktl;
    bf16x8 af = *(const bf16x8*)(xbf + (size_t)(m0 + lm) * 9216 + kt * 32 + lgp * 8);
    int cl = ktl * 32 + lgp * 8;
#pragma unroll
    for (int np = 0; np < 5; ++np) {
      uint4 r0 = *(const uint4*)(w1 + ((size_t)kt * 10 + np * 2 + 0) * 512 + (size_t)l * 8);
      uint4 r1 = *(const uint4*)(w1 + ((size_t)kt * 10 + np * 2 + 1) * 512 + (size_t)l * 8);
      float2 c0 = *(const float2*)&cwl[(cl + 0) * 10 + np * 2];
      float2 c1 = *(const float2*)&cwl[(cl + 1) * 10 + np * 2];
      float2 c2 = *(const float2*)&cwl[(cl + 2) * 10 + np * 2];
      float2 c3 = *(const float2*)&cwl[(cl + 3) * 10 + np * 2];
      float2 c4 = *(const float2*)&cwl[(cl + 4) * 10 + np * 2];
      float2 c5 = *(const float2*)&cwl[(cl + 5) * 10 + np * 2];
      float2 c6 = *(const float2*)&cwl[(cl + 6) * 10 + np * 2];
      float2 c7 = *(const float2*)&cwl[(cl + 7) * 10 + np * 2];
      bf16x8 b0, b1;
      b0[0] = (short)f2bf(bf2f(LOH(r0.x)) * c0.x); b1[0] = (short)f2bf(bf2f(LOH(r1.x)) * c0.y);
      b0[1] = (short)f2bf(bf2f(HIH(r0.x)) * c1.x); b1[1] = (short)f2bf(bf2f(HIH(r1.x)) * c1.y);
      b0[2] = (short)f2bf(bf2f(LOH(r0.y)) * c2.x); b1[2] = (short)f2bf(bf2f(LOH(r1.y)) * c2.y);
      b0[3] = (short)f2bf(bf2f(HIH(r0.y)) * c3.x); b1[3] = (short)f2bf(bf2f(HIH(r1.y)) * c3.y);
      b0[4] = (short)f2bf(bf2f(LOH(r0.z)) * c4.x); b1[4] = (short)f2bf(bf2f(LOH(r1.z)) * c4.y);
      b0[5] = (short)f2bf(bf2f(HIH(r0.z)) * c5.x); b1[5] = (short)f2bf(bf2f(HIH(r1.z)) * c5.y);
      b0[6] = (short)f2bf(bf2f(LOH(r0.w)) * c6.x); b1[6] = (short)f2bf(bf2f(LOH(r1.w)) * c6.y);
      b0[7] = (short)f2bf(bf2f(HIH(r0.w)) * c7.x); b1[7] = (short)f2bf(bf2f(HIH(r1.w)) * c7.y);
      acc[np * 2 + 0] = __builtin_amdgcn_mfma_f32_16x16x32_bf16(af, b0, acc[np * 2 + 0], 0, 0, 0);
      acc[np * 2 + 1] = __builtin_amdgcn_mfma_f32_16x16x32_bf16(af, b1, acc[np * 2 + 1], 0, 0, 0);
    }
  }
  float* pb = part + (size_t)sp * 40960 + (size_t)(m0 + lgp * 4) * 160 + lm;
#pragma unroll
  for (int nt = 0; nt < 10; ++nt)
#pragma unroll
    for (int r = 0; r < 4; ++r)
      pb[r * 160 + nt * 16] = acc[nt][r];
}

// ---------------- R: reduce split-K + squash -> vbfT (or out) ----------------
__global__ void k_r(const float* __restrict__ part, ushort_t* __restrict__ vbfT,
                    float* __restrict__ out, int last) {
  int gtid = blockIdx.x * 256 + threadIdx.x;   // 160 blocks: 40960 elems
  float s = 0.f;
  for (int sp = 0; sp < 48; ++sp) s += part[(size_t)sp * 40960 + gtid];
  float n2 = s * s;
  n2 += __shfl_xor(n2, 1);
  n2 += __shfl_xor(n2, 2);
  n2 += __shfl_xor(n2, 4);
  n2 += __shfl_xor(n2, 8);
  float scale = n2 / ((1.f + n2) * sqrtf(n2));
  float vv = s * scale;
  if (last) {
    out[gtid] = vv;
  } else {
    int b = gtid / 160, uo = gtid - b * 160;
    vbfT[(size_t)uo * 256 + b] = (ushort_t)f2bf(vv);
  }
}

// ---------------- G2: agreement -> ag[it], full-N per block ----------------
// grid (72 mb2, 4 bty), 256 thr = 4 waves; block = 128 k-rows x full N, 1/4 of B.
__global__ __launch_bounds__(256) void k_g2(const ushort_t* __restrict__ xkb,
                                            const ushort_t* __restrict__ vbfT,
                                            const float* __restrict__ wd,
                                            float* __restrict__ ag, int it) {
  int mb2 = blockIdx.x, bty = blockIdx.y;
  int tid = threadIdx.x;
  int wv = tid >> 6, l = tid & 63, lm = l & 15, lgp = l >> 4;
  f32x4 z = {0.f, 0.f, 0.f, 0.f};
  f32x4 acc[2][10];
#pragma unroll
  for (int q = 0; q < 2; ++q)
#pragma unroll
    for (int nt = 0; nt < 10; ++nt) acc[q][nt] = z;
#pragma unroll
  for (int btl = 0; btl < 2; ++btl) {
    int bt = bty * 2 + btl;
    bf16x8 af[2];
#pragma unroll
    for (int q = 0; q < 2; ++q) {
      int mt2 = mb2 * 8 + wv * 2 + q;
      af[q] = *(const bf16x8*)(xkb + (size_t)(mt2 * 16 + lm) * 256 + bt * 32 + lgp * 8);
    }
#pragma unroll
    for (int nt = 0; nt < 10; ++nt) {
      bf16x8 bfr = *(const bf16x8*)(vbfT + (size_t)(nt * 16 + lm) * 256 + bt * 32 + lgp * 8);
      acc[0][nt] = __builtin_amdgcn_mfma_f32_16x16x32_bf16(af[0], bfr, acc[0][nt], 0, 0, 0);
      acc[1][nt] = __builtin_amdgcn_mfma_f32_16x16x32_bf16(af[1], bfr, acc[1][nt], 0, 0, 0);
    }
  }
  float* agt = ag + it * 11520;
#pragma unroll
  for (int q = 0; q < 2; ++q) {
    int mt2 = mb2 * 8 + wv * 2 + q;
#pragma unroll
    for (int nt = 0; nt < 10; ++nt) {
      float4 wdv = *(const float4*)(wd + ((size_t)(mt2 * 10 + nt) * 64 + l) * 4);
      float p0 = acc[q][nt][0] * wdv.x;
      float p1 = acc[q][nt][1] * wdv.y;
      float p2 = acc[q][nt][2] * wdv.z;
      float p3 = acc[q][nt][3] * wdv.w;
#pragma unroll
      for (int off = 1; off < 16; off <<= 1) {
        p0 += __shfl_xor(p0, off);
        p1 += __shfl_xor(p1, off);
        p2 += __shfl_xor(p2, off);
        p3 += __shfl_xor(p3, off);
      }
      if (lm == 0) {
        int krow = mt2 * 16 + lgp * 4;   // rows share i (16 | 1152)
        int c = krow % 1152;
        atomicAdd(&agt[(c + 0) * 10 + nt], p0);
        atomicAdd(&agt[(c + 1) * 10 + nt], p1);
        atomicAdd(&agt[(c + 2) * 10 + nt], p2);
        atomicAdd(&agt[(c + 3) * 10 + nt], p3);
      }
    }
  }
}

extern "C" void kernel_launch(void* const* d_in, const int* in_sizes, int n_in,
                              void* d_out, int out_size, void* d_ws, size_t ws_size,
                              hipStream_t stream) {
  const float* x = (const float*)d_in[0];
  const float* W = (const float*)d_in[1];
  float* out = (float*)d_out;
  char* ws = (char*)d_ws;
  if (ws_size < WS_NEED) return;   // output stays poisoned -> visible failure

  ushort_t* w1   = (ushort_t*)(ws + OFF_W1);
  float*    wd   = (float*)(ws + OFF_WD);
  ushort_t* xbf  = (ushort_t*)(ws + OFF_XBF);
  ushort_t* xkb  = (ushort_t*)(ws + OFF_XKB);
  float*    part = (float*)(ws + OFF_PART);
  ushort_t* vbfT = (ushort_t*)(ws + OFF_VBF);
  float*    ag   = (float*)(ws + OFF_AG);

  k_setup<<<dim3(5796), dim3(256), 0, stream>>>(x, W, w1, wd, xbf, xkb, ag);
  for (int it = 0; it < 4; ++it) {
    k_g1<<<dim3(4, 48), dim3(256), 0, stream>>>(xbf, w1, ag, part, it);
    k_r <<<dim3(160), dim3(256), 0, stream>>>(part, vbfT, out, (it == 3) ? 1 : 0);
    if (it < 3)
      k_g2<<<dim3(72, 4), dim3(256), 0, stream>>>(xkb, vbfT, wd, ag, it);
  }
}

// Round 9
// 160.117 us; speedup vs baseline: 3.6163x; 1.5521x over previous
//
#include <hip/hip_runtime.h>
#include <cstdint>
#include <cstddef>

typedef __attribute__((ext_vector_type(8))) short bf16x8;
typedef __attribute__((ext_vector_type(4))) float f32x4;
typedef unsigned int uint_t;
typedef unsigned short ushort_t;

__device__ __forceinline__ ushort_t f2bf(float f) {
  uint_t u = __float_as_uint(f);
  u += 0x7fffu + ((u >> 16) & 1u);   // RNE
  return (ushort_t)(u >> 16);
}
__device__ __forceinline__ float bf2f(ushort_t h) {
  return __uint_as_float(((uint_t)h) << 16);
}
#define LOH(u) ((ushort_t)((u) & 0xffffu))
#define HIH(u) ((ushort_t)((u) >> 16))

// Workspace offsets (bytes)
#define OFF_W1   0           // 184320*16   = 2,949,120
#define OFF_WD   2949120     // 368640*16   = 5,898,240
#define OFF_XBF  8847360     // 4,718,592
#define OFF_XKB  13565952    // 4,718,592
#define OFF_PART 18284544    // 48*40960*4  = 7,864,320
#define OFF_VBF  26148864    // 160*256*2   = 81,920
#define OFF_AGP  26230784    // 4*2*92160*4 = 2,949,120  (agp[it][bty][c][u][i])
#define WS_NEED  29179904

// ---------------- setup: W frags + xbf + xkb (one launch, 5616 blocks) ----------------
__global__ void k_setup(const float* __restrict__ x, const float* __restrict__ W,
                        ushort_t* __restrict__ w1, float* __restrict__ wd,
                        ushort_t* __restrict__ xbf, ushort_t* __restrict__ xkb) {
  int bid = blockIdx.x, tid = threadIdx.x;
  if (bid < 720) {                       // w1: B-frag bf16 W (184320 frag-lanes)
    int gid = bid * 256 + tid;
    int ll = gid & 63, tile = gid >> 6;
    int nt = tile % 10, kt = tile / 10;
    int lmm = ll & 15, lgg = ll >> 4;
    uint_t pk[4];
#pragma unroll
    for (int jj = 0; jj < 4; ++jj) {
      int k0 = kt * 32 + lgg * 8 + jj * 2;
      int i0 = k0 / 1152, c0 = k0 - i0 * 1152;
      int i1 = (k0 + 1) / 1152, c1 = (k0 + 1) - i1 * 1152;
      ushort_t e0 = f2bf(W[((size_t)(c0 * 10 + nt) * 16 + lmm) * 8 + i0]);
      ushort_t e1 = f2bf(W[((size_t)(c1 * 10 + nt) * 16 + lmm) * 8 + i1]);
      pk[jj] = (uint_t)e0 | ((uint_t)e1 << 16);
    }
    uint4 v; v.x = pk[0]; v.y = pk[1]; v.z = pk[2]; v.w = pk[3];
    *(uint4*)(w1 + (size_t)gid * 8) = v;
  } else if (bid < 2160) {               // wd: D-layout f32 W (368640 frag-lanes)
    int g2 = (bid - 720) * 256 + tid;
    int ll = g2 & 63, tile = g2 >> 6;
    int nt = tile % 10, mt2 = tile / 10;
    int lmm = ll & 15, lgg = ll >> 4;
    float vv[4];
#pragma unroll
    for (int r = 0; r < 4; ++r) {
      int krow = mt2 * 16 + lgg * 4 + r;
      int i = krow / 1152, c = krow - i * 1152;
      vv[r] = W[((size_t)(c * 10 + nt) * 16 + lmm) * 8 + i];
    }
    *(float4*)(wd + (size_t)g2 * 4) = make_float4(vv[0], vv[1], vv[2], vv[3]);
  } else if (bid < 3312) {               // xbf: row-major bf16 x (294912 x8-items)
    int t = (bid - 2160) * 256 + tid;
    const float4 a0 = *(const float4*)(x + (size_t)t * 8);
    const float4 a1 = *(const float4*)(x + (size_t)t * 8 + 4);
    uint4 pk;
    pk.x = (uint_t)f2bf(a0.x) | ((uint_t)f2bf(a0.y) << 16);
    pk.y = (uint_t)f2bf(a0.z) | ((uint_t)f2bf(a0.w) << 16);
    pk.z = (uint_t)f2bf(a1.x) | ((uint_t)f2bf(a1.y) << 16);
    pk.w = (uint_t)f2bf(a1.z) | ((uint_t)f2bf(a1.w) << 16);
    *(uint4*)(xbf + (size_t)t * 8) = pk;
  } else {                               // xkb: transpose tiles (2304 tiles)
    __shared__ float sh[32 * 33];
    int tb = bid - 3312;
    int k0 = (tb % 288) * 32, b0 = (tb / 288) * 32;
    int tx = tid & 31, ty = tid >> 5;
#pragma unroll
    for (int r = 0; r < 32; r += 8)
      sh[(ty + r) * 33 + tx] = x[(size_t)(b0 + ty + r) * 9216 + k0 + tx];
    __syncthreads();
#pragma unroll
    for (int r = 0; r < 32; r += 8)
      xkb[(size_t)(k0 + ty + r) * 256 + b0 + tx] = (ushort_t)f2bf(sh[tx * 33 + ty + r]);
  }
}

// ---------------- G1: part[sp] = xbf * (softmax(agp).*W), full-N per block ----------------
// grid (4 mb4, 48 sp), 256 thr = 4 waves; wave = 16 rows x 160 cols; K-chunk 192.
__global__ __launch_bounds__(256) void k_g1(const ushort_t* __restrict__ xbf,
                                            const ushort_t* __restrict__ w1,
                                            const float* __restrict__ agp,
                                            float* __restrict__ part, int it) {
  int mb4 = blockIdx.x, sp = blockIdx.y;
  int tid = threadIdx.x;
  int wv = tid >> 6, l = tid & 63, lm = l & 15, lgp = l >> 4;
  __shared__ float cwl[192 * 10];
  if (tid < 192) {   // softmax(sum over it slices, bty, i of agp / 256)
    int c = (sp % 6) * 192 + tid;
    float lv[10] = {0.f, 0.f, 0.f, 0.f, 0.f, 0.f, 0.f, 0.f, 0.f, 0.f};
    for (int t = 0; t < it; ++t)
#pragma unroll
      for (int bty = 0; bty < 2; ++bty) {
        const float* a = agp + ((size_t)(t * 2 + bty) * 1152 + c) * 80;
#pragma unroll
        for (int u = 0; u < 10; ++u) {
          float4 s0 = *(const float4*)(a + u * 8);
          float4 s1 = *(const float4*)(a + u * 8 + 4);
          lv[u] += (s0.x + s0.y + s0.z + s0.w) + (s1.x + s1.y + s1.z + s1.w);
        }
      }
    float mx = lv[0];
#pragma unroll
    for (int u = 1; u < 10; ++u) mx = fmaxf(mx, lv[u]);
    float ssum = 0.f;
#pragma unroll
    for (int u = 0; u < 10; ++u) {
      lv[u] = __expf((lv[u] - mx) * (1.0f / 256.0f));
      ssum += lv[u];
    }
    float inv = 1.f / ssum;
#pragma unroll
    for (int u = 0; u < 10; ++u) cwl[tid * 10 + u] = lv[u] * inv;
  }
  __syncthreads();
  f32x4 z = {0.f, 0.f, 0.f, 0.f};
  f32x4 acc[10];
#pragma unroll
  for (int nt = 0; nt < 10; ++nt) acc[nt] = z;
  int m0 = mb4 * 64 + wv * 16;
  for (int ktl = 0; ktl < 6; ++ktl) {
    int kt = sp * 6 + ktl;
    bf16x8 af = *(const bf16x8*)(xbf + (size_t)(m0 + lm) * 9216 + kt * 32 + lgp * 8);
    int cl = ktl * 32 + lgp * 8;
#pragma unroll
    for (int np = 0; np < 5; ++np) {
      uint4 r0 = *(const uint4*)(w1 + ((size_t)kt * 10 + np * 2 + 0) * 512 + (size_t)l * 8);
      uint4 r1 = *(const uint4*)(w1 + ((size_t)kt * 10 + np * 2 + 1) * 512 + (size_t)l * 8);
      float2 c0 = *(const float2*)&cwl[(cl + 0) * 10 + np * 2];
      float2 c1 = *(const float2*)&cwl[(cl + 1) * 10 + np * 2];
      float2 c2 = *(const float2*)&cwl[(cl + 2) * 10 + np * 2];
      float2 c3 = *(const float2*)&cwl[(cl + 3) * 10 + np * 2];
      float2 c4 = *(const float2*)&cwl[(cl + 4) * 10 + np * 2];
      float2 c5 = *(const float2*)&cwl[(cl + 5) * 10 + np * 2];
      float2 c6 = *(const float2*)&cwl[(cl + 6) * 10 + np * 2];
      float2 c7 = *(const float2*)&cwl[(cl + 7) * 10 + np * 2];
      bf16x8 b0, b1;
      b0[0] = (short)f2bf(bf2f(LOH(r0.x)) * c0.x); b1[0] = (short)f2bf(bf2f(LOH(r1.x)) * c0.y);
      b0[1] = (short)f2bf(bf2f(HIH(r0.x)) * c1.x); b1[1] = (short)f2bf(bf2f(HIH(r1.x)) * c1.y);
      b0[2] = (short)f2bf(bf2f(LOH(r0.y)) * c2.x); b1[2] = (short)f2bf(bf2f(LOH(r1.y)) * c2.y);
      b0[3] = (short)f2bf(bf2f(HIH(r0.y)) * c3.x); b1[3] = (short)f2bf(bf2f(HIH(r1.y)) * c3.y);
      b0[4] = (short)f2bf(bf2f(LOH(r0.z)) * c4.x); b1[4] = (short)f2bf(bf2f(LOH(r1.z)) * c4.y);
      b0[5] = (short)f2bf(bf2f(HIH(r0.z)) * c5.x); b1[5] = (short)f2bf(bf2f(HIH(r1.z)) * c5.y);
      b0[6] = (short)f2bf(bf2f(LOH(r0.w)) * c6.x); b1[6] = (short)f2bf(bf2f(LOH(r1.w)) * c6.y);
      b0[7] = (short)f2bf(bf2f(HIH(r0.w)) * c7.x); b1[7] = (short)f2bf(bf2f(HIH(r1.w)) * c7.y);
      acc[np * 2 + 0] = __builtin_amdgcn_mfma_f32_16x16x32_bf16(af, b0, acc[np * 2 + 0], 0, 0, 0);
      acc[np * 2 + 1] = __builtin_amdgcn_mfma_f32_16x16x32_bf16(af, b1, acc[np * 2 + 1], 0, 0, 0);
    }
  }
  float* pb = part + (size_t)sp * 40960 + (size_t)(m0 + lgp * 4) * 160 + lm;
#pragma unroll
  for (int nt = 0; nt < 10; ++nt)
#pragma unroll
    for (int r = 0; r < 4; ++r)
      pb[r * 160 + nt * 16] = acc[nt][r];
}

// ---------------- R: reduce split-K + squash -> vbfT (or out) ----------------
__global__ void k_r(const float* __restrict__ part, ushort_t* __restrict__ vbfT,
                    float* __restrict__ out, int last) {
  int gtid = blockIdx.x * 256 + threadIdx.x;   // 160 blocks: 40960 elems
  float s = 0.f;
  for (int sp = 0; sp < 48; ++sp) s += part[(size_t)sp * 40960 + gtid];
  float n2 = s * s;
  n2 += __shfl_xor(n2, 1);
  n2 += __shfl_xor(n2, 2);
  n2 += __shfl_xor(n2, 4);
  n2 += __shfl_xor(n2, 8);
  float scale = n2 / ((1.f + n2) * sqrtf(n2));
  float vv = s * scale;
  if (last) {
    out[gtid] = vv;
  } else {
    int b = gtid / 160, uo = gtid - b * 160;
    vbfT[(size_t)uo * 256 + b] = (ushort_t)f2bf(vv);
  }
}

// ---------------- G2: agreement -> agp[it][bty] (NO atomics) ----------------
// grid (144 mb2, 2 bty), 256 thr = 4 waves; wave = 1 mt2 (16 krows), half of B.
__global__ __launch_bounds__(256) void k_g2(const ushort_t* __restrict__ xkb,
                                            const ushort_t* __restrict__ vbfT,
                                            const float* __restrict__ wd,
                                            float* __restrict__ agp, int it) {
  int mb2 = blockIdx.x, bty = blockIdx.y;
  int tid = threadIdx.x;
  int wv = tid >> 6, l = tid & 63, lm = l & 15, lgp = l >> 4;
  int mt2 = mb2 * 4 + wv;
  f32x4 z = {0.f, 0.f, 0.f, 0.f};
  f32x4 acc[10];
#pragma unroll
  for (int nt = 0; nt < 10; ++nt) acc[nt] = z;
#pragma unroll
  for (int btl = 0; btl < 4; ++btl) {
    int bt = bty * 4 + btl;
    bf16x8 af = *(const bf16x8*)(xkb + (size_t)(mt2 * 16 + lm) * 256 + bt * 32 + lgp * 8);
#pragma unroll
    for (int nt = 0; nt < 10; ++nt) {
      bf16x8 bfr = *(const bf16x8*)(vbfT + (size_t)(nt * 16 + lm) * 256 + bt * 32 + lgp * 8);
      acc[nt] = __builtin_amdgcn_mfma_f32_16x16x32_bf16(af, bfr, acc[nt], 0, 0, 0);
    }
  }
  // epilogue: dot with W (D-layout), reduce over o (16 lanes), single-writer store
  float* agt = agp + ((size_t)it * 2 + bty) * 92160;   // [c][u][i] layout: (c*10+u)*8+i
#pragma unroll
  for (int nt = 0; nt < 10; ++nt) {
    float4 wdv = *(const float4*)(wd + ((size_t)(mt2 * 10 + nt) * 64 + l) * 4);
    float p0 = acc[nt][0] * wdv.x;
    float p1 = acc[nt][1] * wdv.y;
    float p2 = acc[nt][2] * wdv.z;
    float p3 = acc[nt][3] * wdv.w;
#pragma unroll
    for (int off = 1; off < 16; off <<= 1) {
      p0 += __shfl_xor(p0, off);
      p1 += __shfl_xor(p1, off);
      p2 += __shfl_xor(p2, off);
      p3 += __shfl_xor(p3, off);
    }
    if (lm == 0) {
      int krow = mt2 * 16 + lgp * 4;      // 4 consecutive krows share i (16 | 1152)
      int i = krow / 1152, c = krow - i * 1152;
      agt[(size_t)((c + 0) * 10 + nt) * 8 + i] = p0;
      agt[(size_t)((c + 1) * 10 + nt) * 8 + i] = p1;
      agt[(size_t)((c + 2) * 10 + nt) * 8 + i] = p2;
      agt[(size_t)((c + 3) * 10 + nt) * 8 + i] = p3;
    }
  }
}

extern "C" void kernel_launch(void* const* d_in, const int* in_sizes, int n_in,
                              void* d_out, int out_size, void* d_ws, size_t ws_size,
                              hipStream_t stream) {
  const float* x = (const float*)d_in[0];
  const float* W = (const float*)d_in[1];
  float* out = (float*)d_out;
  char* ws = (char*)d_ws;
  if (ws_size < WS_NEED) return;   // output stays poisoned -> visible failure

  ushort_t* w1   = (ushort_t*)(ws + OFF_W1);
  float*    wd   = (float*)(ws + OFF_WD);
  ushort_t* xbf  = (ushort_t*)(ws + OFF_XBF);
  ushort_t* xkb  = (ushort_t*)(ws + OFF_XKB);
  float*    part = (float*)(ws + OFF_PART);
  ushort_t* vbfT = (ushort_t*)(ws + OFF_VBF);
  float*    agp  = (float*)(ws + OFF_AGP);

  k_setup<<<dim3(5616), dim3(256), 0, stream>>>(x, W, w1, wd, xbf, xkb);
  for (int it = 0; it < 4; ++it) {
    k_g1<<<dim3(4, 48), dim3(256), 0, stream>>>(xbf, w1, agp, part, it);
    k_r <<<dim3(160), dim3(256), 0, stream>>>(part, vbfT, out, (it == 3) ? 1 : 0);
    if (it < 3)
      k_g2<<<dim3(144, 2), dim3(256), 0, stream>>>(xkb, vbfT, wd, agp, it);
  }
}